// Round 1
// baseline (436.060 us; speedup 1.0000x reference)
//
#include <hip/hip_runtime.h>
#include <hip/hip_bf16.h>

typedef unsigned short u16;
typedef unsigned long long u64;
typedef __bf16 bfv8 __attribute__((ext_vector_type(8)));
typedef float fv4 __attribute__((ext_vector_type(4)));

// ---- helpers ----
static __device__ __forceinline__ u16 f2bf(float f) {
    unsigned u = __builtin_bit_cast(unsigned, f);
    unsigned r = (u + 0x7fffu + ((u >> 16) & 1u)) >> 16;
    return (u16)r;
}

static __device__ __forceinline__ void gld16(const void* g, void* l) {
    __builtin_amdgcn_global_load_lds(
        (const __attribute__((address_space(1))) void*)g,
        (__attribute__((address_space(3))) void*)l, 16, 0, 0);
}

// ---------------------------------------------------------------------------
// Kernel 0: fp32 -> bf16 conversion of x, Wq, Wk, Wv, Wo (contiguous in ws)
// ---------------------------------------------------------------------------
__global__ __launch_bounds__(256) void cvt_f32_bf16(
    const float* __restrict__ x, const float* __restrict__ wq,
    const float* __restrict__ wk, const float* __restrict__ wv,
    const float* __restrict__ wo, u16* __restrict__ dst)
{
    int i = blockIdx.x * 256 + threadIdx.x;      // float4 index
    const int NX4 = 6291456 / 4;                 // 1572864
    const int NW4 = 589824 / 4;                  // 147456
    const float4* src;
    int j = i;
    if (j < NX4) { src = (const float4*)x; }
    else {
        j -= NX4;
        if (j < NW4) { src = (const float4*)wq; }
        else {
            j -= NW4;
            if (j < NW4) { src = (const float4*)wk; }
            else {
                j -= NW4;
                if (j < NW4) { src = (const float4*)wv; }
                else { j -= NW4; src = (const float4*)wo; }
            }
        }
    }
    float4 v = src[j];
    u64 pk = (u64)f2bf(v.x) | ((u64)f2bf(v.y) << 16) |
             ((u64)f2bf(v.z) << 32) | ((u64)f2bf(v.w) << 48);
    *(u64*)(dst + (size_t)i * 4) = pk;
}

// ---------------------------------------------------------------------------
// Generic GEMM: C[M=8192][N=768] = A[8192][768] @ Bw[768][768]^T + bias
// A, Bw bf16 row-major (K contiguous).  Tile 128x128, BK=32, 4 waves.
// mode 0: write bf16 to [B,H,N,Dh] head layout (q,k)
// mode 1: write bf16 to [B,H,Dh,N] (v transposed)
// mode 2: write fp32 row-major (final output)
// ---------------------------------------------------------------------------
__global__ __launch_bounds__(256) void gemm_bt(
    const u16* __restrict__ A, const u16* __restrict__ Bw,
    const float* __restrict__ bias, u16* __restrict__ Cb,
    float* __restrict__ Cf, int mode)
{
    __shared__ alignas(16) u16 lA[128 * 32];
    __shared__ alignas(16) u16 lB[128 * 32];
    const int t = threadIdx.x;
    const int w = t >> 6, l = t & 63;
    const int l15 = l & 15, l4 = l >> 4;
    const int bx = blockIdx.x, by = blockIdx.y;
    const int wr = (w >> 1) * 64, wc = (w & 1) * 64;
    const int srow = t >> 2;   // 0..63 staging row within half
    const int sg = t & 3;      // lds chunk position (8 elems each)

    fv4 acc[4][4] = {};

    for (int kt = 0; kt < 24; ++kt) {
        const int kof = kt * 32;
        #pragma unroll
        for (int is = 0; is < 2; ++is) {
            int row = is * 64 + srow;
            int gs = sg ^ ((row >> 1) & 3);   // pre-swizzled source chunk
            gld16(A + (size_t)(bx * 128 + row) * 768 + kof + gs * 8,
                  &lA[row * 32 + sg * 8]);
            gld16(Bw + (size_t)(by * 128 + row) * 768 + kof + gs * 8,
                  &lB[row * 32 + sg * 8]);
        }
        __syncthreads();

        bfv8 aF[4], bF[4];
        #pragma unroll
        for (int f = 0; f < 4; ++f) {
            int ra = wr + f * 16 + l15;
            aF[f] = *(const bfv8*)&lA[ra * 32 + (l4 ^ ((ra >> 1) & 3)) * 8];
            int rb = wc + f * 16 + l15;
            bF[f] = *(const bfv8*)&lB[rb * 32 + (l4 ^ ((rb >> 1) & 3)) * 8];
        }
        #pragma unroll
        for (int fm = 0; fm < 4; ++fm)
            #pragma unroll
            for (int fn = 0; fn < 4; ++fn)
                acc[fm][fn] = __builtin_amdgcn_mfma_f32_16x16x32_bf16(
                    aF[fm], bF[fn], acc[fm][fn], 0, 0, 0);
        __syncthreads();
    }

    // epilogue: C row = token m, col = output channel n
    #pragma unroll
    for (int fm = 0; fm < 4; ++fm) {
        #pragma unroll
        for (int fn = 0; fn < 4; ++fn) {
            int n = by * 128 + wc + fn * 16 + l15;
            float bs = bias[n];
            #pragma unroll
            for (int rr = 0; rr < 4; ++rr) {
                int m = bx * 128 + wr + fm * 16 + l4 * 4 + rr;
                float v = acc[fm][fn][rr] + bs;
                if (mode == 2) {
                    Cf[(size_t)m * 768 + n] = v;
                } else {
                    int b = m >> 10, tok = m & 1023;
                    int h = n >> 6, dl = n & 63;
                    size_t addr = (mode == 0)
                        ? (((size_t)(b * 12 + h) * 1024 + tok) * 64 + dl)
                        : (((size_t)(b * 12 + h) * 64 + dl) * 1024 + tok);
                    Cb[addr] = f2bf(v);
                }
            }
        }
    }
}

// ---------------------------------------------------------------------------
// Scores + head-softmax.  WG = (b, 32 n-rows), 4 waves:
//   wave w: n-subtile (w&1)*16, m-half (w>>1)*512.
// Computes S^T = mfma(K, Q) for all 12 heads so each lane holds the full
// 12-head vector for its (n,m) pairs -> in-lane softmax over heads.
// attn[b][h][n][m] bf16, m contiguous (packed 4-wide stores).
// ---------------------------------------------------------------------------
__global__ __launch_bounds__(256, 1) void scores_smax(
    const u16* __restrict__ qb, const u16* __restrict__ kb,
    u16* __restrict__ attn, int b0)
{
    __shared__ alignas(16) u16 lK[2 * 12 * 32 * 64];   // 96 KB, [half][h][ml][d]
    const int t = threadIdx.x;
    const int w = t >> 6, l = t & 63;
    const int l15 = l & 15, l4 = l >> 4;
    const int bl = blockIdx.y;       // chunk-local batch
    const int b = b0 + bl;           // true batch
    const int nsub = w & 1, mh = w >> 1;
    const int nbase = blockIdx.x * 32 + nsub * 16;

    // Q fragments: 12 heads x 2 k-steps (B-operand: col = token n = l15)
    bfv8 Qf[12][2];
    #pragma unroll
    for (int h = 0; h < 12; ++h)
        #pragma unroll
        for (int ks = 0; ks < 2; ++ks)
            Qf[h][ks] = *(const bfv8*)(qb +
                ((size_t)(b * 12 + h) * 1024 + nbase + l15) * 64 + ks * 32 + l4 * 8);

    // staging thread mapping
    const int sml = t >> 3;             // 0..31 (m row within tile)
    const int sgp = t & 7;              // lds chunk pos (8 elems of d)
    const int sgs = sgp ^ (sml & 7);    // pre-swizzled source chunk

    for (int mt = 0; mt < 16; ++mt) {
        #pragma unroll
        for (int p = 0; p < 2; ++p)
            #pragma unroll
            for (int h = 0; h < 12; ++h)
                gld16(kb + ((size_t)(b * 12 + h) * 1024 + p * 512 + mt * 32 + sml) * 64 + sgs * 8,
                      &lK[p * 24576 + h * 2048 + sml * 64 + sgp * 8]);
        __syncthreads();

        fv4 S[12][2];
        #pragma unroll
        for (int h = 0; h < 12; ++h) {
            #pragma unroll
            for (int mf = 0; mf < 2; ++mf) {
                fv4 s = {};
                #pragma unroll
                for (int ks = 0; ks < 2; ++ks) {
                    int ml = mf * 16 + l15;
                    int gd = ks * 4 + l4;
                    bfv8 kf = *(const bfv8*)&lK[mh * 24576 + h * 2048 + ml * 64 +
                                                (gd ^ (ml & 7)) * 8];
                    s = __builtin_amdgcn_mfma_f32_16x16x32_bf16(kf, Qf[h][ks], s, 0, 0, 0);
                }
                S[h][mf] = s;
            }
        }

        // softmax over the 12 heads, per (mf, rr) = per fixed (n, m); in-lane.
        #pragma unroll
        for (int mf = 0; mf < 2; ++mf) {
            #pragma unroll
            for (int rr = 0; rr < 4; ++rr) {
                float mx = S[0][mf][rr];
                #pragma unroll
                for (int h = 1; h < 12; ++h) mx = fmaxf(mx, S[h][mf][rr]);
                float pp[12];
                float sum = 0.f;
                #pragma unroll
                for (int h = 0; h < 12; ++h) {
                    pp[h] = __builtin_amdgcn_exp2f((S[h][mf][rr] - mx) *
                                                   (0.125f * 1.44269504f));
                    sum += pp[h];
                }
                float r = __builtin_amdgcn_rcpf(sum);
                #pragma unroll
                for (int h = 0; h < 12; ++h) S[h][mf][rr] = pp[h] * r;
            }
        }

        // store: S^T layout -> rr are m-adjacent: pack 4 bf16 = 8 B
        #pragma unroll
        for (int h = 0; h < 12; ++h) {
            #pragma unroll
            for (int mf = 0; mf < 2; ++mf) {
                u64 pk = (u64)f2bf(S[h][mf][0]) | ((u64)f2bf(S[h][mf][1]) << 16) |
                         ((u64)f2bf(S[h][mf][2]) << 32) | ((u64)f2bf(S[h][mf][3]) << 48);
                size_t m = (size_t)mh * 512 + mt * 32 + mf * 16 + l4 * 4;
                *(u64*)(attn + ((size_t)(bl * 12 + h) * 1024 + nbase + l15) * 1024 + m) = pk;
            }
        }
        __syncthreads();
    }
}

// ---------------------------------------------------------------------------
// PV: ctx[b][tok][h*64+dl] = sum_m attn[b,h,tok,m] * V[b,h,m,dl]
// per WG: (n-tile 64, h, b); vtb is [B,H,Dh,N] so both operands k-contiguous.
// ---------------------------------------------------------------------------
__global__ __launch_bounds__(256) void pv_gemm(
    const u16* __restrict__ attn, const u16* __restrict__ vtb,
    u16* __restrict__ ctx, int b0)
{
    __shared__ alignas(16) u16 lA[64 * 64];
    __shared__ alignas(16) u16 lV[64 * 64];
    const int t = threadIdx.x, w = t >> 6, l = t & 63;
    const int l15 = l & 15, l4 = l >> 4;
    const int bx = blockIdx.x, h = blockIdx.y, bl = blockIdx.z;
    const int b = b0 + bl;
    const int srow0 = t >> 3, sgp = t & 7;
    const int sgs = sgp ^ (srow0 & 7);

    fv4 acc[4] = {};
    const size_t abase = ((size_t)(bl * 12 + h) * 1024 + bx * 64) * 1024;
    const size_t vbase = (size_t)(b * 12 + h) * 64 * 1024;

    for (int mt = 0; mt < 16; ++mt) {
        #pragma unroll
        for (int is = 0; is < 2; ++is) {
            int row = is * 32 + srow0;
            gld16(attn + abase + (size_t)row * 1024 + mt * 64 + sgs * 8,
                  &lA[row * 64 + sgp * 8]);
            gld16(vtb + vbase + (size_t)row * 1024 + mt * 64 + sgs * 8,
                  &lV[row * 64 + sgp * 8]);
        }
        __syncthreads();

        #pragma unroll
        for (int ks = 0; ks < 2; ++ks) {
            int ra = w * 16 + l15;
            int gd = ks * 4 + l4;
            bfv8 aF = *(const bfv8*)&lA[ra * 64 + (gd ^ (ra & 7)) * 8];
            #pragma unroll
            for (int dn = 0; dn < 4; ++dn) {
                int rv = dn * 16 + l15;
                bfv8 vF = *(const bfv8*)&lV[rv * 64 + (gd ^ (rv & 7)) * 8];
                acc[dn] = __builtin_amdgcn_mfma_f32_16x16x32_bf16(aF, vF, acc[dn], 0, 0, 0);
            }
        }
        __syncthreads();
    }

    #pragma unroll
    for (int dn = 0; dn < 4; ++dn) {
        #pragma unroll
        for (int rr = 0; rr < 4; ++rr) {
            int tok = bx * 64 + w * 16 + l4 * 4 + rr;
            int dl = dn * 16 + l15;
            ctx[((size_t)b * 1024 + tok) * 768 + h * 64 + dl] = f2bf(acc[dn][rr]);
        }
    }
}

// ---------------------------------------------------------------------------
extern "C" void kernel_launch(void* const* d_in, const int* in_sizes, int n_in,
                              void* d_out, int out_size, void* d_ws, size_t ws_size,
                              hipStream_t stream)
{
    const float* x  = (const float*)d_in[0];
    const float* Wq = (const float*)d_in[1];
    const float* bq = (const float*)d_in[2];
    const float* Wk = (const float*)d_in[3];
    const float* bk = (const float*)d_in[4];
    const float* Wv = (const float*)d_in[5];
    const float* bv = (const float*)d_in[6];
    const float* Wo = (const float*)d_in[7];
    const float* bo = (const float*)d_in[8];
    float* out = (float*)d_out;

    u16* ws  = (u16*)d_ws;
    u16* xb  = ws;                      // 6291456 elems (x as bf16)
    u16* wqb = xb + 6291456;            // 589824 each
    u16* wkb = wqb + 589824;
    u16* wvb = wkb + 589824;
    u16* wob = wvb + 589824;
    u16* qb  = wob + 589824;            // [B,H,N,Dh] 6291456
    u16* kbuf= qb + 6291456;            // [B,H,N,Dh]
    u16* vtb = kbuf + 6291456;          // [B,H,Dh,N]
    u16* ctx = vtb + 6291456;           // [B,N,D]
    u16* attnb = ctx + 6291456;         // attn chunk

    const size_t FIXED_BYTES = (size_t)(attnb - ws) * 2;
    size_t avail = ws_size > FIXED_BYTES ? ws_size - FIXED_BYTES : 0;
    int nb = 8;                          // batches per chunk
    while (nb > 1 && (size_t)nb * 25165824ull > avail) nb >>= 1;
    int nchunks = 8 / nb;

    cvt_f32_bf16<<<dim3(8448), dim3(256), 0, stream>>>(x, Wq, Wk, Wv, Wo, ws);

    gemm_bt<<<dim3(64, 6), dim3(256), 0, stream>>>(xb, wqb, bq, qb, nullptr, 0);
    gemm_bt<<<dim3(64, 6), dim3(256), 0, stream>>>(xb, wkb, bk, kbuf, nullptr, 0);
    gemm_bt<<<dim3(64, 6), dim3(256), 0, stream>>>(xb, wvb, bv, vtb, nullptr, 1);

    for (int c = 0; c < nchunks; ++c) {
        scores_smax<<<dim3(32, nb), dim3(256), 0, stream>>>(qb, kbuf, attnb, c * nb);
        pv_gemm<<<dim3(16, 12, nb), dim3(256), 0, stream>>>(attnb, vtb, ctx, c * nb);
    }

    gemm_bt<<<dim3(64, 6), dim3(256), 0, stream>>>(ctx, wob, bo, nullptr, out, 2);
}